// Round 1
// baseline (583.217 us; speedup 1.0000x reference)
//
#include <hip/hip_runtime.h>
#include <hip/hip_bf16.h>

// B=4, N=2048, D=1024, H=16, HD=64
#define BATCH 4
#define NSEQ 2048
#define DMODEL 1024
#define NHEAD 16
#define HDIM 64

typedef __attribute__((ext_vector_type(8))) short short8;
typedef __attribute__((ext_vector_type(4))) float f32x4;
typedef unsigned short ushort_t;

__device__ __forceinline__ ushort_t f2bf(float f) {
    union { float f; unsigned u; } x; x.f = f;
    unsigned r = x.u + 0x7fffu + ((x.u >> 16) & 1u);   // round-to-nearest-even
    return (ushort_t)(r >> 16);
}

// ---------------- fp32 -> bf16 convert (vectorized) ----------------
__global__ __launch_bounds__(256) void cvt_f32_bf16(const float* __restrict__ in,
                                                    ushort_t* __restrict__ out, int n) {
    int i = (blockIdx.x * 256 + threadIdx.x) * 8;
    if (i >= n) return;
    float4 f0 = *(const float4*)(in + i);
    float4 f1 = *(const float4*)(in + i + 4);
    short8 o;
    o[0] = f2bf(f0.x); o[1] = f2bf(f0.y); o[2] = f2bf(f0.z); o[3] = f2bf(f0.w);
    o[4] = f2bf(f1.x); o[5] = f2bf(f1.y); o[6] = f2bf(f1.z); o[7] = f2bf(f1.w);
    *(short8*)(out + i) = o;
}

// ---------------- bf16 GEMM: C[M][N] = A[M][K] * Bt[N][K]^T ----------------
// 128x128 block tile, BK=32, 4 waves (2x2), each wave 64x64 via 4x4 16x16x32 MFMA.
__device__ __forceinline__ void storeC(float* C, size_t idx, float v) { C[idx] = v; }
__device__ __forceinline__ void storeC(ushort_t* C, size_t idx, float v) { C[idx] = f2bf(v); }

template <typename OutT>
__global__ __launch_bounds__(256) void gemm_bt(const ushort_t* __restrict__ A,
                                               const ushort_t* __restrict__ Bt,
                                               OutT* __restrict__ C,
                                               int M, int N, int K, float alpha) {
    __shared__ ushort_t As[128][40];   // +8 pad: 80B row stride, conflict-free-ish
    __shared__ ushort_t Bs[128][40];
    int tid = threadIdx.x;
    int l = tid & 63, w = tid >> 6;
    int wm = w >> 1, wn = w & 1;
    int lr = l & 15, lk = l >> 4;
    int nb = N >> 7;
    int brow = (blockIdx.x / nb) << 7;
    int bcol = (blockIdx.x % nb) << 7;

    f32x4 acc[4][4] = {};

    for (int k0 = 0; k0 < K; k0 += 32) {
        // stage A/B tiles: 128 rows x 32 cols bf16 = 512 x 16B chunks each
#pragma unroll
        for (int c = tid; c < 512; c += 256) {
            int row = c >> 2, cc = (c & 3) << 3;
            *(short8*)&As[row][cc] = *(const short8*)(A + (size_t)(brow + row) * K + k0 + cc);
            *(short8*)&Bs[row][cc] = *(const short8*)(Bt + (size_t)(bcol + row) * K + k0 + cc);
        }
        __syncthreads();
        short8 af[4], bf_[4];
#pragma unroll
        for (int m = 0; m < 4; m++) af[m]  = *(const short8*)&As[wm * 64 + m * 16 + lr][8 * lk];
#pragma unroll
        for (int n = 0; n < 4; n++) bf_[n] = *(const short8*)&Bs[wn * 64 + n * 16 + lr][8 * lk];
#pragma unroll
        for (int m = 0; m < 4; m++)
#pragma unroll
            for (int n = 0; n < 4; n++)
                acc[m][n] = __builtin_amdgcn_mfma_f32_16x16x32_bf16(af[m], bf_[n], acc[m][n], 0, 0, 0);
        __syncthreads();
    }
#pragma unroll
    for (int m = 0; m < 4; m++)
#pragma unroll
        for (int n = 0; n < 4; n++)
#pragma unroll
            for (int r = 0; r < 4; r++) {
                int row = brow + wm * 64 + m * 16 + lk * 4 + r;
                int col = bcol + wn * 64 + n * 16 + lr;
                storeC(C, (size_t)row * N + col, acc[m][n][r] * alpha);
            }
}

// ---------------- causal flash attention ----------------
// grid: (B*H) * (N/64) blocks; 4 waves/block, wave w owns q rows [qt*64+w*16, +16).
// KV tiles of 32 rows staged in LDS; online softmax; P via LDS round-trip.
__global__ __launch_bounds__(256) void attn_kernel(const ushort_t* __restrict__ Qp,
                                                   const ushort_t* __restrict__ Kp,
                                                   const ushort_t* __restrict__ Vp,
                                                   ushort_t* __restrict__ AO) {
    __shared__ ushort_t Ks[32][72];   // 64 + 8 pad
    __shared__ ushort_t Vs[32][72];
    __shared__ ushort_t Ps[4][16][40];

    int tid = threadIdx.x;
    int l = tid & 63, w = tid >> 6;
    int lr = l & 15, lk = l >> 4;
    int bid = blockIdx.x;
    int qt = bid & 31;         // 32 q-tiles of 64 rows
    int bh = bid >> 5;         // 0..63
    int b = bh >> 4, h = bh & 15;

    const size_t base = ((size_t)b * NSEQ) * DMODEL + (size_t)h * HDIM;

    int qrow0 = qt * 64 + w * 16;
    // Q fragments (16 rows x 64 d), 2 k-chunks of 32
    short8 qf[2];
    {
        const ushort_t* qp = Qp + base + (size_t)(qrow0 + lr) * DMODEL + 8 * lk;
        qf[0] = *(const short8*)(qp);
        qf[1] = *(const short8*)(qp + 32);
    }
    f32x4 O[4] = {};
    float mrow[4], lrow[4];
#pragma unroll
    for (int r = 0; r < 4; r++) { mrow[r] = -1e30f; lrow[r] = 0.f; }

    int q_last = qrow0 + 15;
    int jmax = (qt * 64 + 64) / 32;   // uniform across block
    for (int j = 0; j < jmax; ++j) {
        {   // stage K,V rows [j*32, +32) x 64 cols: 256 chunks of 16B each
            int row = tid >> 3, cc = (tid & 7) * 8;
            const ushort_t* kp = Kp + base + (size_t)(j * 32 + row) * DMODEL + cc;
            const ushort_t* vp = Vp + base + (size_t)(j * 32 + row) * DMODEL + cc;
            *(short8*)&Ks[row][cc] = *(const short8*)kp;
            *(short8*)&Vs[row][cc] = *(const short8*)vp;
        }
        __syncthreads();
        bool active = (j * 32 <= q_last);
        if (active) {
            // S[16q][32k] = Q Kt  (two 16x16 col-blocks)
            f32x4 S[2];
#pragma unroll
            for (int kc = 0; kc < 2; kc++) {
                short8 kf0 = *(const short8*)&Ks[kc * 16 + lr][8 * lk];
                short8 kf1 = *(const short8*)&Ks[kc * 16 + lr][32 + 8 * lk];
                f32x4 a = {0.f, 0.f, 0.f, 0.f};
                a = __builtin_amdgcn_mfma_f32_16x16x32_bf16(qf[0], kf0, a, 0, 0, 0);
                a = __builtin_amdgcn_mfma_f32_16x16x32_bf16(qf[1], kf1, a, 0, 0, 0);
                S[kc] = a;
            }
            // mask + online softmax (rows = lk*4+r, cols = lane lr within 16-group)
#pragma unroll
            for (int r = 0; r < 4; r++) {
                int qr = qrow0 + lk * 4 + r;
                float s0 = S[0][r], s1 = S[1][r];
                if (j * 32 + lr > qr)      s0 = -1e30f;
                if (j * 32 + 16 + lr > qr) s1 = -1e30f;
                float t = fmaxf(s0, s1);
                t = fmaxf(t, __shfl_xor(t, 1));
                t = fmaxf(t, __shfl_xor(t, 2));
                t = fmaxf(t, __shfl_xor(t, 4));
                t = fmaxf(t, __shfl_xor(t, 8));
                float mn = fmaxf(mrow[r], t);
                float sc = __expf(mrow[r] - mn);
                float p0 = __expf(s0 - mn), p1 = __expf(s1 - mn);
                float rs = p0 + p1;
                rs += __shfl_xor(rs, 1);
                rs += __shfl_xor(rs, 2);
                rs += __shfl_xor(rs, 4);
                rs += __shfl_xor(rs, 8);
                lrow[r] = lrow[r] * sc + rs;
                mrow[r] = mn;
#pragma unroll
                for (int n = 0; n < 4; n++) O[n][r] *= sc;
                Ps[w][lk * 4 + r][lr]      = f2bf(p0);
                Ps[w][lk * 4 + r][16 + lr] = f2bf(p1);
            }
        }
        __syncthreads();
        if (active) {
            short8 pf = *(const short8*)&Ps[w][lr][8 * lk];
#pragma unroll
            for (int n = 0; n < 4; n++) {
                short8 vf;
#pragma unroll
                for (int i = 0; i < 8; i++) vf[i] = Vs[8 * lk + i][n * 16 + lr];
                O[n] = __builtin_amdgcn_mfma_f32_16x16x32_bf16(pf, vf, O[n], 0, 0, 0);
            }
        }
        __syncthreads();
    }
    // epilogue: O /= l, store bf16
#pragma unroll
    for (int r = 0; r < 4; r++) {
        float inv = 1.f / lrow[r];
        int row = lk * 4 + r;
#pragma unroll
        for (int n = 0; n < 4; n++) {
            AO[base + (size_t)(qrow0 + row) * DMODEL + n * 16 + lr] = f2bf(O[n][r] * inv);
        }
    }
}

// ---------------- launch ----------------
extern "C" void kernel_launch(void* const* d_in, const int* in_sizes, int n_in,
                              void* d_out, int out_size, void* d_ws, size_t ws_size,
                              hipStream_t stream) {
    const float* q  = (const float*)d_in[0];
    const float* k  = (const float*)d_in[1];
    const float* v  = (const float*)d_in[2];
    const float* Wq = (const float*)d_in[3];
    const float* Wk = (const float*)d_in[4];
    const float* Wv = (const float*)d_in[5];
    const float* Wo = (const float*)d_in[6];
    float* out = (float*)d_out;

    const size_t BND = (size_t)BATCH * NSEQ * DMODEL;   // 8388608
    const size_t WSZ = (size_t)DMODEL * DMODEL;         // 1048576
    const size_t need = (7 * BND + 4 * WSZ) * sizeof(ushort_t);  // ~120 MB
    if (ws_size < need) return;  // insufficient workspace -> harness will flag

    ushort_t* ws  = (ushort_t*)d_ws;
    ushort_t* qb  = ws;
    ushort_t* kb  = qb + BND;
    ushort_t* vb  = kb + BND;
    ushort_t* Qp  = vb + BND;
    ushort_t* Kp  = Qp + BND;
    ushort_t* Vp  = Kp + BND;
    ushort_t* AO  = Vp + BND;
    ushort_t* Wqb = AO + BND;
    ushort_t* Wkb = Wqb + WSZ;
    ushort_t* Wvb = Wkb + WSZ;
    ushort_t* Wob = Wvb + WSZ;

    const int M = BATCH * NSEQ;  // 8192

    cvt_f32_bf16<<<(int)(BND / 8 / 256), 256, 0, stream>>>(q, qb, (int)BND);
    cvt_f32_bf16<<<(int)(BND / 8 / 256), 256, 0, stream>>>(k, kb, (int)BND);
    cvt_f32_bf16<<<(int)(BND / 8 / 256), 256, 0, stream>>>(v, vb, (int)BND);
    cvt_f32_bf16<<<(int)(WSZ / 8 / 256), 256, 0, stream>>>(Wq, Wqb, (int)WSZ);
    cvt_f32_bf16<<<(int)(WSZ / 8 / 256), 256, 0, stream>>>(Wk, Wkb, (int)WSZ);
    cvt_f32_bf16<<<(int)(WSZ / 8 / 256), 256, 0, stream>>>(Wv, Wvb, (int)WSZ);
    cvt_f32_bf16<<<(int)(WSZ / 8 / 256), 256, 0, stream>>>(Wo, Wob, (int)WSZ);

    int gblocks = (M / 128) * (DMODEL / 128);  // 512
    // scores scale 1/sqrt(64) folded into Q projection (exact in bf16)
    gemm_bt<ushort_t><<<gblocks, 256, 0, stream>>>(qb, Wqb, Qp, M, DMODEL, DMODEL, 0.125f);
    gemm_bt<ushort_t><<<gblocks, 256, 0, stream>>>(kb, Wkb, Kp, M, DMODEL, DMODEL, 1.0f);
    gemm_bt<ushort_t><<<gblocks, 256, 0, stream>>>(vb, Wvb, Vp, M, DMODEL, DMODEL, 1.0f);

    attn_kernel<<<BATCH * NHEAD * (NSEQ / 64), 256, 0, stream>>>(Qp, Kp, Vp, AO);

    gemm_bt<float><<<gblocks, 256, 0, stream>>>(AO, Wob, out, M, DMODEL, DMODEL, 1.0f);
}

// Round 2
// 524.363 us; speedup vs baseline: 1.1122x; 1.1122x over previous
//
#include <hip/hip_runtime.h>
#include <hip/hip_bf16.h>

// B=4, N=2048, D=1024, H=16, HD=64
#define BATCH 4
#define NSEQ 2048
#define DMODEL 1024
#define NHEAD 16
#define HDIM 64

typedef __attribute__((ext_vector_type(8))) short short8;
typedef __attribute__((ext_vector_type(4))) float f32x4;
typedef unsigned short ushort_t;

__device__ __forceinline__ ushort_t f2bf(float f) {
    union { float f; unsigned u; } x; x.f = f;
    unsigned r = x.u + 0x7fffu + ((x.u >> 16) & 1u);   // round-to-nearest-even
    return (ushort_t)(r >> 16);
}

// ---------------- fp32 -> bf16 convert (vectorized) ----------------
__global__ __launch_bounds__(256) void cvt_f32_bf16(const float* __restrict__ in,
                                                    ushort_t* __restrict__ out, int n) {
    int i = (blockIdx.x * 256 + threadIdx.x) * 8;
    if (i >= n) return;
    float4 f0 = *(const float4*)(in + i);
    float4 f1 = *(const float4*)(in + i + 4);
    short8 o;
    o[0] = f2bf(f0.x); o[1] = f2bf(f0.y); o[2] = f2bf(f0.z); o[3] = f2bf(f0.w);
    o[4] = f2bf(f1.x); o[5] = f2bf(f1.y); o[6] = f2bf(f1.z); o[7] = f2bf(f1.w);
    *(short8*)(out + i) = o;
}

// ---------------- bf16 GEMM: C[M][N] = A[M][K] * Bt[N][K]^T ----------------
// 128x128 block tile, BK=32, 4 waves (2x2), each wave 64x64 via 4x4 16x16x32 MFMA.
// TRANS=true writes output in VT layout: VT[(b*DMODEL + col)*NSEQ + row%NSEQ]
__device__ __forceinline__ void storeC(float* C, size_t idx, float v) { C[idx] = v; }
__device__ __forceinline__ void storeC(ushort_t* C, size_t idx, float v) { C[idx] = f2bf(v); }

template <typename OutT, bool TRANS>
__global__ __launch_bounds__(256) void gemm_bt(const ushort_t* __restrict__ A,
                                               const ushort_t* __restrict__ Bt,
                                               OutT* __restrict__ C,
                                               int M, int N, int K, float alpha) {
    __shared__ ushort_t As[128][40];   // +8 pad
    __shared__ ushort_t Bs[128][40];
    int tid = threadIdx.x;
    int l = tid & 63, w = tid >> 6;
    int wm = w >> 1, wn = w & 1;
    int lr = l & 15, lk = l >> 4;
    int nb = N >> 7;
    int brow = (blockIdx.x / nb) << 7;
    int bcol = (blockIdx.x % nb) << 7;

    f32x4 acc[4][4] = {};

    for (int k0 = 0; k0 < K; k0 += 32) {
#pragma unroll
        for (int c = tid; c < 512; c += 256) {
            int row = c >> 2, cc = (c & 3) << 3;
            *(short8*)&As[row][cc] = *(const short8*)(A + (size_t)(brow + row) * K + k0 + cc);
            *(short8*)&Bs[row][cc] = *(const short8*)(Bt + (size_t)(bcol + row) * K + k0 + cc);
        }
        __syncthreads();
        short8 af[4], bf_[4];
#pragma unroll
        for (int m = 0; m < 4; m++) af[m]  = *(const short8*)&As[wm * 64 + m * 16 + lr][8 * lk];
#pragma unroll
        for (int n = 0; n < 4; n++) bf_[n] = *(const short8*)&Bs[wn * 64 + n * 16 + lr][8 * lk];
#pragma unroll
        for (int m = 0; m < 4; m++)
#pragma unroll
            for (int n = 0; n < 4; n++)
                acc[m][n] = __builtin_amdgcn_mfma_f32_16x16x32_bf16(af[m], bf_[n], acc[m][n], 0, 0, 0);
        __syncthreads();
    }
#pragma unroll
    for (int m = 0; m < 4; m++)
#pragma unroll
        for (int n = 0; n < 4; n++)
#pragma unroll
            for (int r = 0; r < 4; r++) {
                int row = brow + wm * 64 + m * 16 + lk * 4 + r;
                int col = bcol + wn * 64 + n * 16 + lr;
                if (TRANS) {
                    // VT[(b*DMODEL + col)][row % NSEQ], leading dim NSEQ
                    int b = row >> 11, nl = row & (NSEQ - 1);
                    storeC(C, (size_t)(b * DMODEL + col) * NSEQ + nl, acc[m][n][r] * alpha);
                } else {
                    storeC(C, (size_t)row * N + col, acc[m][n][r] * alpha);
                }
            }
}

// ---------------- causal flash attention, barrier-free ----------------
// grid: (B*H) * (N/128) blocks; 4 waves/block; wave w owns q rows [qt*128+w*32, +32).
// K read directly from global (L2-resident); V read from transposed VT layout.
// Only LDS use: wave-local P re-layout (no __syncthreads anywhere).
__global__ __launch_bounds__(256) void attn_kernel(const ushort_t* __restrict__ Qp,
                                                   const ushort_t* __restrict__ Kp,
                                                   const ushort_t* __restrict__ VT,
                                                   ushort_t* __restrict__ AO) {
    __shared__ ushort_t Ps[4][32][40];

    int tid = threadIdx.x;
    int l = tid & 63, w = tid >> 6;
    int lr = l & 15, lk = l >> 4;
    int bid = blockIdx.x;
    int qt = bid & 15;         // 16 q-tiles of 128 rows per head
    int bh = bid >> 4;         // 0..63
    int b = bh >> 4, h = bh & 15;

    const size_t base  = ((size_t)b * NSEQ) * DMODEL + (size_t)h * HDIM;
    const size_t baseT = (size_t)bh * HDIM * NSEQ;

    int qrow0 = qt * 128 + w * 32;

    // Q fragments: 2 row-blocks x (2 k-chunks of 32)
    short8 qf[2][2];
#pragma unroll
    for (int m = 0; m < 2; m++) {
        const ushort_t* qp = Qp + base + (size_t)(qrow0 + m * 16 + lr) * DMODEL + 8 * lk;
        qf[m][0] = *(const short8*)(qp);
        qf[m][1] = *(const short8*)(qp + 32);
    }

    f32x4 O[2][4] = {};
    float mrow[2][4], lrow[2][4];
#pragma unroll
    for (int m = 0; m < 2; m++)
#pragma unroll
        for (int r = 0; r < 4; r++) { mrow[m][r] = -1e30f; lrow[m][r] = 0.f; }

    int jmax = (qrow0 >> 5) + 1;   // per-wave causal bound (tiles of 32)
    for (int j = 0; j < jmax; ++j) {
        int k0 = j * 32;
        // ---- S[32q][32k] = Q K^T ----
        f32x4 S[2][2];
#pragma unroll
        for (int kc = 0; kc < 2; kc++) {
            const ushort_t* kp = Kp + base + (size_t)(k0 + kc * 16 + lr) * DMODEL + 8 * lk;
            short8 kf0 = *(const short8*)(kp);
            short8 kf1 = *(const short8*)(kp + 32);
#pragma unroll
            for (int m = 0; m < 2; m++) {
                f32x4 a = {0.f, 0.f, 0.f, 0.f};
                a = __builtin_amdgcn_mfma_f32_16x16x32_bf16(qf[m][0], kf0, a, 0, 0, 0);
                a = __builtin_amdgcn_mfma_f32_16x16x32_bf16(qf[m][1], kf1, a, 0, 0, 0);
                S[m][kc] = a;
            }
        }
        bool maskt = (j == jmax - 1);
        // ---- online softmax (rows = m*16 + lk*4 + r, col within block = lr) ----
#pragma unroll
        for (int m = 0; m < 2; m++)
#pragma unroll
            for (int r = 0; r < 4; r++) {
                int qr = qrow0 + m * 16 + lk * 4 + r;
                float s0 = S[m][0][r], s1 = S[m][1][r];
                if (maskt) {
                    if (k0 + lr > qr)      s0 = -1e30f;
                    if (k0 + 16 + lr > qr) s1 = -1e30f;
                }
                float t = fmaxf(s0, s1);
                t = fmaxf(t, __shfl_xor(t, 1));
                t = fmaxf(t, __shfl_xor(t, 2));
                t = fmaxf(t, __shfl_xor(t, 4));
                t = fmaxf(t, __shfl_xor(t, 8));
                float mn = fmaxf(mrow[m][r], t);
                float sc = __expf(mrow[m][r] - mn);
                float p0 = __expf(s0 - mn), p1 = __expf(s1 - mn);
                float rs = p0 + p1;
                rs += __shfl_xor(rs, 1);
                rs += __shfl_xor(rs, 2);
                rs += __shfl_xor(rs, 4);
                rs += __shfl_xor(rs, 8);
                lrow[m][r] = lrow[m][r] * sc + rs;
                mrow[m][r] = mn;
#pragma unroll
                for (int n = 0; n < 4; n++) O[m][n][r] *= sc;
                Ps[w][m * 16 + lk * 4 + r][lr]      = f2bf(p0);
                Ps[w][m * 16 + lk * 4 + r][16 + lr] = f2bf(p1);
            }
        // ---- O += P V  (V from transposed layout: contiguous k) ----
        short8 pf[2];
#pragma unroll
        for (int m = 0; m < 2; m++) pf[m] = *(const short8*)&Ps[w][m * 16 + lr][8 * lk];
#pragma unroll
        for (int n = 0; n < 4; n++) {
            short8 vf = *(const short8*)(VT + baseT + (size_t)(n * 16 + lr) * NSEQ + k0 + 8 * lk);
#pragma unroll
            for (int m = 0; m < 2; m++)
                O[m][n] = __builtin_amdgcn_mfma_f32_16x16x32_bf16(pf[m], vf, O[m][n], 0, 0, 0);
        }
    }
    // epilogue
#pragma unroll
    for (int m = 0; m < 2; m++)
#pragma unroll
        for (int r = 0; r < 4; r++) {
            float inv = 1.f / lrow[m][r];
            int row = qrow0 + m * 16 + lk * 4 + r;
#pragma unroll
            for (int n = 0; n < 4; n++) {
                AO[base + (size_t)row * DMODEL + n * 16 + lr] = f2bf(O[m][n][r] * inv);
            }
        }
}

// ---------------- launch ----------------
extern "C" void kernel_launch(void* const* d_in, const int* in_sizes, int n_in,
                              void* d_out, int out_size, void* d_ws, size_t ws_size,
                              hipStream_t stream) {
    const float* q  = (const float*)d_in[0];
    const float* k  = (const float*)d_in[1];
    const float* v  = (const float*)d_in[2];
    const float* Wq = (const float*)d_in[3];
    const float* Wk = (const float*)d_in[4];
    const float* Wv = (const float*)d_in[5];
    const float* Wo = (const float*)d_in[6];
    float* out = (float*)d_out;

    const size_t BND = (size_t)BATCH * NSEQ * DMODEL;   // 8388608
    const size_t WSZ = (size_t)DMODEL * DMODEL;         // 1048576
    const size_t need = (7 * BND + 4 * WSZ) * sizeof(ushort_t);  // ~120 MB
    if (ws_size < need) return;

    ushort_t* ws  = (ushort_t*)d_ws;
    ushort_t* qb  = ws;
    ushort_t* kb  = qb + BND;
    ushort_t* vb  = kb + BND;
    ushort_t* Qp  = vb + BND;
    ushort_t* Kp  = Qp + BND;
    ushort_t* VT  = Kp + BND;   // V projection, transposed layout [B*D][NSEQ]
    ushort_t* AO  = VT + BND;
    ushort_t* Wqb = AO + BND;
    ushort_t* Wkb = Wqb + WSZ;
    ushort_t* Wvb = Wkb + WSZ;
    ushort_t* Wob = Wvb + WSZ;

    const int M = BATCH * NSEQ;  // 8192

    cvt_f32_bf16<<<(int)(BND / 8 / 256), 256, 0, stream>>>(q, qb, (int)BND);
    cvt_f32_bf16<<<(int)(BND / 8 / 256), 256, 0, stream>>>(k, kb, (int)BND);
    cvt_f32_bf16<<<(int)(BND / 8 / 256), 256, 0, stream>>>(v, vb, (int)BND);
    cvt_f32_bf16<<<(int)(WSZ / 8 / 256), 256, 0, stream>>>(Wq, Wqb, (int)WSZ);
    cvt_f32_bf16<<<(int)(WSZ / 8 / 256), 256, 0, stream>>>(Wk, Wkb, (int)WSZ);
    cvt_f32_bf16<<<(int)(WSZ / 8 / 256), 256, 0, stream>>>(Wv, Wvb, (int)WSZ);
    cvt_f32_bf16<<<(int)(WSZ / 8 / 256), 256, 0, stream>>>(Wo, Wob, (int)WSZ);

    int gblocks = (M / 128) * (DMODEL / 128);  // 512
    // scores scale 1/sqrt(64) folded into Q projection (exact in bf16)
    gemm_bt<ushort_t, false><<<gblocks, 256, 0, stream>>>(qb, Wqb, Qp, M, DMODEL, DMODEL, 0.125f);
    gemm_bt<ushort_t, false><<<gblocks, 256, 0, stream>>>(kb, Wkb, Kp, M, DMODEL, DMODEL, 1.0f);
    gemm_bt<ushort_t, true ><<<gblocks, 256, 0, stream>>>(vb, Wvb, VT, M, DMODEL, DMODEL, 1.0f);

    attn_kernel<<<BATCH * NHEAD * (NSEQ / 128), 256, 0, stream>>>(Qp, Kp, VT, AO);

    gemm_bt<float, false><<<gblocks, 256, 0, stream>>>(AO, Wob, out, M, DMODEL, DMODEL, 1.0f);
}

// Round 3
// 318.380 us; speedup vs baseline: 1.8318x; 1.6470x over previous
//
#include <hip/hip_runtime.h>
#include <hip/hip_bf16.h>

// B=4, N=2048, D=1024, H=16, HD=64
#define BATCH 4
#define NSEQ 2048
#define DMODEL 1024
#define NHEAD 16
#define HDIM 64

typedef __attribute__((ext_vector_type(8))) short short8;
typedef __attribute__((ext_vector_type(4))) float f32x4;
typedef unsigned short ushort_t;

__device__ __forceinline__ ushort_t f2bf(float f) {
    union { float f; unsigned u; } x; x.f = f;
    unsigned r = x.u + 0x7fffu + ((x.u >> 16) & 1u);   // round-to-nearest-even
    return (ushort_t)(r >> 16);
}

// ---------------- fp32 -> bf16 convert (vectorized) ----------------
__global__ __launch_bounds__(256) void cvt_f32_bf16(const float* __restrict__ in,
                                                    ushort_t* __restrict__ out, int n) {
    int i = (blockIdx.x * 256 + threadIdx.x) * 8;
    if (i >= n) return;
    float4 f0 = *(const float4*)(in + i);
    float4 f1 = *(const float4*)(in + i + 4);
    short8 o;
    o[0] = f2bf(f0.x); o[1] = f2bf(f0.y); o[2] = f2bf(f0.z); o[3] = f2bf(f0.w);
    o[4] = f2bf(f1.x); o[5] = f2bf(f1.y); o[6] = f2bf(f1.z); o[7] = f2bf(f1.w);
    *(short8*)(out + i) = o;
}

// ---------------- bf16 GEMM: C[M][N] = A[M][K] * Bt[N][K]^T ----------------
__device__ __forceinline__ void storeC(float* C, size_t idx, float v) { C[idx] = v; }
__device__ __forceinline__ void storeC(ushort_t* C, size_t idx, float v) { C[idx] = f2bf(v); }

template <typename OutT, bool TRANS>
__global__ __launch_bounds__(256) void gemm_bt(const ushort_t* __restrict__ A,
                                               const ushort_t* __restrict__ Bt,
                                               OutT* __restrict__ C,
                                               int M, int N, int K, float alpha) {
    __shared__ ushort_t As[128][40];   // +8 pad
    __shared__ ushort_t Bs[128][40];
    int tid = threadIdx.x;
    int l = tid & 63, w = tid >> 6;
    int wm = w >> 1, wn = w & 1;
    int lr = l & 15, lk = l >> 4;
    int nb = N >> 7;
    int brow = (blockIdx.x / nb) << 7;
    int bcol = (blockIdx.x % nb) << 7;

    f32x4 acc[4][4] = {};

    for (int k0 = 0; k0 < K; k0 += 32) {
#pragma unroll
        for (int c = tid; c < 512; c += 256) {
            int row = c >> 2, cc = (c & 3) << 3;
            *(short8*)&As[row][cc] = *(const short8*)(A + (size_t)(brow + row) * K + k0 + cc);
            *(short8*)&Bs[row][cc] = *(const short8*)(Bt + (size_t)(bcol + row) * K + k0 + cc);
        }
        __syncthreads();
        short8 af[4], bf_[4];
#pragma unroll
        for (int m = 0; m < 4; m++) af[m]  = *(const short8*)&As[wm * 64 + m * 16 + lr][8 * lk];
#pragma unroll
        for (int n = 0; n < 4; n++) bf_[n] = *(const short8*)&Bs[wn * 64 + n * 16 + lr][8 * lk];
#pragma unroll
        for (int m = 0; m < 4; m++)
#pragma unroll
            for (int n = 0; n < 4; n++)
                acc[m][n] = __builtin_amdgcn_mfma_f32_16x16x32_bf16(af[m], bf_[n], acc[m][n], 0, 0, 0);
        __syncthreads();
    }
#pragma unroll
    for (int m = 0; m < 4; m++)
#pragma unroll
        for (int n = 0; n < 4; n++)
#pragma unroll
            for (int r = 0; r < 4; r++) {
                int row = brow + wm * 64 + m * 16 + lk * 4 + r;
                int col = bcol + wn * 64 + n * 16 + lr;
                if (TRANS) {
                    int b = row >> 11, nl = row & (NSEQ - 1);
                    storeC(C, (size_t)(b * DMODEL + col) * NSEQ + nl, acc[m][n][r] * alpha);
                } else {
                    storeC(C, (size_t)row * N + col, acc[m][n][r] * alpha);
                }
            }
}

// ---------------- causal flash attention: swapped QK^T, in-register softmax ----
// grid: 1024 blocks (bh = bid&63, qt = 15 - bid>>6 descending work order).
// 4 waves/block; wave w owns q rows [qt*128 + w*32, +32) as two 16-col blocks.
// S^T = mfma(K, Q): lane holds 16 S values of ONE q-row -> in-register softmax.
// O^T = mfma(V^T, P^T): V^T A-frags contiguous from VT; P^T via wave-local LDS.
__global__ __launch_bounds__(256) void attn_kernel(const ushort_t* __restrict__ Qp,
                                                   const ushort_t* __restrict__ Kp,
                                                   const ushort_t* __restrict__ VT,
                                                   ushort_t* __restrict__ AO) {
    __shared__ ushort_t Ps[4][32][72];

    int tid = threadIdx.x;
    int l = tid & 63, w = tid >> 6;
    int lr = l & 15, lk = l >> 4;
    int bid = blockIdx.x;
    int bh = bid & 63;
    int qt = 15 - (bid >> 6);      // heavy tiles first
    int b = bh >> 4, h = bh & 15;

    const size_t base  = ((size_t)b * NSEQ) * DMODEL + (size_t)h * HDIM;
    const size_t baseT = (size_t)bh * HDIM * NSEQ;

    int qrow0 = qt * 128 + w * 32;

    // Q as B-operand: lane provides Q[q=qrow0+16*qm+lr][d=32*c+8*lk..+7]
    short8 qf[2][2];
#pragma unroll
    for (int qm = 0; qm < 2; qm++) {
        const ushort_t* qp = Qp + base + (size_t)(qrow0 + 16 * qm + lr) * DMODEL + 8 * lk;
        qf[qm][0] = *(const short8*)(qp);
        qf[qm][1] = *(const short8*)(qp + 32);
    }

    f32x4 O[2][4] = {};                       // O^T fragments: [qm][d-block n]
    float mrow[2] = {-1e30f, -1e30f};
    float lrow[2] = {0.f, 0.f};

    int jmax = (qrow0 >> 6) + 1;              // KV tiles of 64
    for (int j = 0; j < jmax; ++j) {
        int k0 = j << 6;
        // K as A-operand: lane provides K[k=k0+16*kb+lr][d=32*c+8*lk..+7]
        short8 kf[4][2];
#pragma unroll
        for (int kb = 0; kb < 4; kb++) {
            const ushort_t* kp = Kp + base + (size_t)(k0 + 16 * kb + lr) * DMODEL + 8 * lk;
            kf[kb][0] = *(const short8*)(kp);
            kf[kb][1] = *(const short8*)(kp + 32);
        }
        // V^T as A-operand: lane provides VT[d=16*n+lr][k=k0+32*c+8*lk..+7]
        short8 vf[4][2];
#pragma unroll
        for (int n = 0; n < 4; n++) {
            const ushort_t* vp = VT + baseT + (size_t)(16 * n + lr) * NSEQ + k0 + 8 * lk;
            vf[n][0] = *(const short8*)(vp);
            vf[n][1] = *(const short8*)(vp + 32);
        }
        bool maskt = (j == jmax - 1);
#pragma unroll
        for (int qm = 0; qm < 2; qm++) {
            // S^T[k][q]: lane holds k = 16*kb + 4*lk + r, q = lr
            f32x4 S[4];
#pragma unroll
            for (int kb = 0; kb < 4; kb++) {
                f32x4 a = {0.f, 0.f, 0.f, 0.f};
                a = __builtin_amdgcn_mfma_f32_16x16x32_bf16(kf[kb][0], qf[qm][0], a, 0, 0, 0);
                a = __builtin_amdgcn_mfma_f32_16x16x32_bf16(kf[kb][1], qf[qm][1], a, 0, 0, 0);
                S[kb] = a;
            }
            int qg = qrow0 + 16 * qm + lr;
            if (maskt) {
#pragma unroll
                for (int kb = 0; kb < 4; kb++)
#pragma unroll
                    for (int r = 0; r < 4; r++)
                        if (k0 + 16 * kb + 4 * lk + r > qg) S[kb][r] = -1e30f;
            }
            // row max: in-register tree + 2 shfl (lanes lr, lr+16, lr+32, lr+48)
            float m0 = fmaxf(fmaxf(S[0][0], S[0][1]), fmaxf(S[0][2], S[0][3]));
            float m1 = fmaxf(fmaxf(S[1][0], S[1][1]), fmaxf(S[1][2], S[1][3]));
            float m2 = fmaxf(fmaxf(S[2][0], S[2][1]), fmaxf(S[2][2], S[2][3]));
            float m3 = fmaxf(fmaxf(S[3][0], S[3][1]), fmaxf(S[3][2], S[3][3]));
            float mx = fmaxf(fmaxf(m0, m1), fmaxf(m2, m3));
            mx = fmaxf(mx, __shfl_xor(mx, 16));
            mx = fmaxf(mx, __shfl_xor(mx, 32));
            float mn = fmaxf(mrow[qm], mx);
            float sc = __expf(mrow[qm] - mn);
            mrow[qm] = mn;
#pragma unroll
            for (int kb = 0; kb < 4; kb++)
#pragma unroll
                for (int r = 0; r < 4; r++)
                    S[kb][r] = __expf(S[kb][r] - mn);
            float s0 = (S[0][0] + S[0][1]) + (S[0][2] + S[0][3]);
            float s1 = (S[1][0] + S[1][1]) + (S[1][2] + S[1][3]);
            float s2 = (S[2][0] + S[2][1]) + (S[2][2] + S[2][3]);
            float s3 = (S[3][0] + S[3][1]) + (S[3][2] + S[3][3]);
            float rs = (s0 + s1) + (s2 + s3);
            rs += __shfl_xor(rs, 16);
            rs += __shfl_xor(rs, 32);
            lrow[qm] = lrow[qm] * sc + rs;
#pragma unroll
            for (int n = 0; n < 4; n++)
#pragma unroll
                for (int r = 0; r < 4; r++)
                    O[qm][n][r] *= sc;
            // pack P^T to LDS: Ps[q][k], 8 u32 writes per lane
#pragma unroll
            for (int kb = 0; kb < 4; kb++) {
                unsigned pa = (unsigned)f2bf(S[kb][0]) | ((unsigned)f2bf(S[kb][1]) << 16);
                unsigned pb = (unsigned)f2bf(S[kb][2]) | ((unsigned)f2bf(S[kb][3]) << 16);
                *(unsigned*)&Ps[w][qm * 16 + lr][16 * kb + 4 * lk]     = pa;
                *(unsigned*)&Ps[w][qm * 16 + lr][16 * kb + 4 * lk + 2] = pb;
            }
        }
        // PV: O^T += V^T P^T (wave-local LDS, no barrier)
#pragma unroll
        for (int qm = 0; qm < 2; qm++) {
            short8 pf0 = *(const short8*)&Ps[w][qm * 16 + lr][8 * lk];
            short8 pf1 = *(const short8*)&Ps[w][qm * 16 + lr][32 + 8 * lk];
#pragma unroll
            for (int n = 0; n < 4; n++) {
                O[qm][n] = __builtin_amdgcn_mfma_f32_16x16x32_bf16(vf[n][0], pf0, O[qm][n], 0, 0, 0);
                O[qm][n] = __builtin_amdgcn_mfma_f32_16x16x32_bf16(vf[n][1], pf1, O[qm][n], 0, 0, 0);
            }
        }
    }
    // epilogue: lane holds O^T[d=16*n+4*lk+r][q=lr]; write packed pairs
#pragma unroll
    for (int qm = 0; qm < 2; qm++) {
        float inv = 1.f / lrow[qm];
        size_t rowoff = base + (size_t)(qrow0 + 16 * qm + lr) * DMODEL;
#pragma unroll
        for (int n = 0; n < 4; n++)
#pragma unroll
            for (int s = 0; s < 2; s++) {
                unsigned pk = (unsigned)f2bf(O[qm][n][2 * s] * inv) |
                              ((unsigned)f2bf(O[qm][n][2 * s + 1] * inv) << 16);
                *(unsigned*)(AO + rowoff + 16 * n + 4 * lk + 2 * s) = pk;
            }
    }
}

// ---------------- launch ----------------
extern "C" void kernel_launch(void* const* d_in, const int* in_sizes, int n_in,
                              void* d_out, int out_size, void* d_ws, size_t ws_size,
                              hipStream_t stream) {
    const float* q  = (const float*)d_in[0];
    const float* k  = (const float*)d_in[1];
    const float* v  = (const float*)d_in[2];
    const float* Wq = (const float*)d_in[3];
    const float* Wk = (const float*)d_in[4];
    const float* Wv = (const float*)d_in[5];
    const float* Wo = (const float*)d_in[6];
    float* out = (float*)d_out;

    const size_t BND = (size_t)BATCH * NSEQ * DMODEL;   // 8388608
    const size_t WSZ = (size_t)DMODEL * DMODEL;         // 1048576
    const size_t need = (7 * BND + 4 * WSZ) * sizeof(ushort_t);  // ~120 MB
    if (ws_size < need) return;

    ushort_t* ws  = (ushort_t*)d_ws;
    ushort_t* qb  = ws;
    ushort_t* kb  = qb + BND;
    ushort_t* vb  = kb + BND;
    ushort_t* Qp  = vb + BND;
    ushort_t* Kp  = Qp + BND;
    ushort_t* VT  = Kp + BND;   // V projection, transposed layout [B*D][NSEQ]
    ushort_t* AO  = VT + BND;
    ushort_t* Wqb = AO + BND;
    ushort_t* Wkb = Wqb + WSZ;
    ushort_t* Wvb = Wkb + WSZ;
    ushort_t* Wob = Wvb + WSZ;

    const int M = BATCH * NSEQ;  // 8192

    cvt_f32_bf16<<<(int)(BND / 8 / 256), 256, 0, stream>>>(q, qb, (int)BND);
    cvt_f32_bf16<<<(int)(BND / 8 / 256), 256, 0, stream>>>(k, kb, (int)BND);
    cvt_f32_bf16<<<(int)(BND / 8 / 256), 256, 0, stream>>>(v, vb, (int)BND);
    cvt_f32_bf16<<<(int)(WSZ / 8 / 256), 256, 0, stream>>>(Wq, Wqb, (int)WSZ);
    cvt_f32_bf16<<<(int)(WSZ / 8 / 256), 256, 0, stream>>>(Wk, Wkb, (int)WSZ);
    cvt_f32_bf16<<<(int)(WSZ / 8 / 256), 256, 0, stream>>>(Wv, Wvb, (int)WSZ);
    cvt_f32_bf16<<<(int)(WSZ / 8 / 256), 256, 0, stream>>>(Wo, Wob, (int)WSZ);

    int gblocks = (M / 128) * (DMODEL / 128);  // 512
    // scores scale 1/sqrt(64) folded into Q projection (exact in bf16)
    gemm_bt<ushort_t, false><<<gblocks, 256, 0, stream>>>(qb, Wqb, Qp, M, DMODEL, DMODEL, 0.125f);
    gemm_bt<ushort_t, false><<<gblocks, 256, 0, stream>>>(kb, Wkb, Kp, M, DMODEL, DMODEL, 1.0f);
    gemm_bt<ushort_t, true ><<<gblocks, 256, 0, stream>>>(vb, Wvb, VT, M, DMODEL, DMODEL, 1.0f);

    attn_kernel<<<BATCH * NHEAD * (NSEQ / 128), 256, 0, stream>>>(Qp, Kp, VT, AO);

    gemm_bt<float, false><<<gblocks, 256, 0, stream>>>(AO, Wob, out, M, DMODEL, DMODEL, 1.0f);
}

// Round 4
// 299.165 us; speedup vs baseline: 1.9495x; 1.0642x over previous
//
#include <hip/hip_runtime.h>
#include <hip/hip_bf16.h>

// B=4, N=2048, D=1024, H=16, HD=64
#define BATCH 4
#define NSEQ 2048
#define DMODEL 1024
#define NHEAD 16
#define HDIM 64

typedef __attribute__((ext_vector_type(8))) short short8;
typedef __attribute__((ext_vector_type(4))) float f32x4;
typedef __attribute__((ext_vector_type(16))) float f32x16;
typedef __attribute__((ext_vector_type(2))) int int2v;
typedef unsigned short ushort_t;

__device__ __forceinline__ ushort_t f2bf(float f) {
    union { float f; unsigned u; } x; x.f = f;
    unsigned r = x.u + 0x7fffu + ((x.u >> 16) & 1u);   // round-to-nearest-even
    return (ushort_t)(r >> 16);
}

__device__ __forceinline__ unsigned cvt_pk_bf16(float lo, float hi) {
    unsigned r;
    asm("v_cvt_pk_bf16_f32 %0, %1, %2" : "=v"(r) : "v"(lo), "v"(hi));
    return r;
}

// async global->LDS, 16B per lane, dest = wave-uniform base + lane*16
#define GLOAD16(gp, lp) __builtin_amdgcn_global_load_lds(                       \
    (const __attribute__((address_space(1))) unsigned*)(const void*)(gp),       \
    (__attribute__((address_space(3))) unsigned*)(void*)(lp), 16, 0, 0)

// ---------------- fp32 -> bf16 convert (vectorized) ----------------
__global__ __launch_bounds__(256) void cvt_f32_bf16(const float* __restrict__ in,
                                                    ushort_t* __restrict__ out, int n) {
    int i = (blockIdx.x * 256 + threadIdx.x) * 8;
    if (i >= n) return;
    float4 f0 = *(const float4*)(in + i);
    float4 f1 = *(const float4*)(in + i + 4);
    short8 o;
    o[0] = f2bf(f0.x); o[1] = f2bf(f0.y); o[2] = f2bf(f0.z); o[3] = f2bf(f0.w);
    o[4] = f2bf(f1.x); o[5] = f2bf(f1.y); o[6] = f2bf(f1.z); o[7] = f2bf(f1.w);
    *(short8*)(out + i) = o;
}

// ---------------- bf16 GEMM (m97 staging): C[M][N] = A[M][K] * Bt[N][K]^T ----
__device__ __forceinline__ void storeC(float* C, size_t idx, float v) { C[idx] = v; }
__device__ __forceinline__ void storeC(ushort_t* C, size_t idx, float v) { C[idx] = f2bf(v); }

template <typename OutT, bool TRANS>
__global__ __launch_bounds__(256) void gemm_bt(const ushort_t* __restrict__ A,
                                               const ushort_t* __restrict__ Bt,
                                               OutT* __restrict__ C,
                                               int M, int N, int K, float alpha) {
    __shared__ ushort_t As[128 * 32];   // linear, no pad (global_load_lds dest)
    __shared__ ushort_t Bs[128 * 32];
    int tid = threadIdx.x;
    int l = tid & 63, w = tid >> 6;
    int wm = w >> 1, wn = w & 1;
    int lr = l & 15, lk = l >> 4;
    int nb = N >> 7;
    int brow = (blockIdx.x / nb) << 7;
    int bcol = (blockIdx.x % nb) << 7;

    // staging: wave w covers rows [w*32, w*32+32); lane l -> row +=(l>>2), col 8*(l&3)
    int srow = w * 32 + (l >> 2);
    int scol = (l & 3) * 8;
    const ushort_t* pA = A + (size_t)(brow + srow) * K + scol;
    const ushort_t* pB = Bt + (size_t)(bcol + srow) * K + scol;
    ushort_t* ldsA0 = &As[(w * 32) * 32];
    ushort_t* ldsA1 = &As[(w * 32 + 16) * 32];
    ushort_t* ldsB0 = &Bs[(w * 32) * 32];
    ushort_t* ldsB1 = &Bs[(w * 32 + 16) * 32];
    const size_t rowK16 = (size_t)16 * K;

    f32x4 acc[4][4] = {};

    for (int k0 = 0; k0 < K; k0 += 32) {
        GLOAD16(pA + k0, ldsA0);
        GLOAD16(pA + k0 + rowK16, ldsA1);
        GLOAD16(pB + k0, ldsB0);
        GLOAD16(pB + k0 + rowK16, ldsB1);
        __syncthreads();
        short8 af[4], bf_[4];
#pragma unroll
        for (int m = 0; m < 4; m++) af[m]  = *(const short8*)&As[(wm * 64 + m * 16 + lr) * 32 + 8 * lk];
#pragma unroll
        for (int n = 0; n < 4; n++) bf_[n] = *(const short8*)&Bs[(wn * 64 + n * 16 + lr) * 32 + 8 * lk];
#pragma unroll
        for (int m = 0; m < 4; m++)
#pragma unroll
            for (int n = 0; n < 4; n++)
                acc[m][n] = __builtin_amdgcn_mfma_f32_16x16x32_bf16(af[m], bf_[n], acc[m][n], 0, 0, 0);
        __syncthreads();
    }
#pragma unroll
    for (int m = 0; m < 4; m++)
#pragma unroll
        for (int n = 0; n < 4; n++)
#pragma unroll
            for (int r = 0; r < 4; r++) {
                int row = brow + wm * 64 + m * 16 + lk * 4 + r;
                int col = bcol + wn * 64 + n * 16 + lr;
                if (TRANS) {
                    int b = row >> 11, nl = row & (NSEQ - 1);
                    storeC(C, (size_t)(b * DMODEL + col) * NSEQ + nl, acc[m][n][r] * alpha);
                } else {
                    storeC(C, (size_t)row * N + col, acc[m][n][r] * alpha);
                }
            }
}

// ---------------- causal flash attention: 32x32 MFMA, zero LDS ----------------
// grid: 1024 blocks (bh = bid&63, qt = 15 - bid>>6); 4 waves; wave owns 32 q rows.
// S^T = mfma32(K, Q): lane holds 16 S for q = lane&31, k = (r&3)+8*(r>>2)+4*hi.
// P^T redistribution: cvt_pk pairs + permlane32_swap (T12) -> B-operand, no LDS.
// O^T = mfma32(V^T, P^T). Softmax in exp2 domain (log2e folded into Q scale).
__global__ __launch_bounds__(256) void attn_kernel(const ushort_t* __restrict__ Qp,
                                                   const ushort_t* __restrict__ Kp,
                                                   const ushort_t* __restrict__ VT,
                                                   ushort_t* __restrict__ AO) {
    int tid = threadIdx.x;
    int l = tid & 63, w = tid >> 6;
    int lq = l & 31;            // q column
    int hi = l >> 5;            // lane half
    int bid = blockIdx.x;
    int bh = bid & 63;
    int qt = 15 - (bid >> 6);   // heavy tiles first
    int b = bh >> 4, h = bh & 15;

    const size_t base  = ((size_t)b * NSEQ) * DMODEL + (size_t)h * HDIM;
    const size_t baseT = (size_t)bh * HDIM * NSEQ;

    int qrow0 = qt * 128 + w * 32;
    int qg = qrow0 + lq;

    // Q as B-operand: qf[c] = Q[qg][16c + 8hi .. +7]
    short8 qf[4];
    {
        const ushort_t* qp = Qp + base + (size_t)qg * DMODEL + 8 * hi;
#pragma unroll
        for (int c = 0; c < 4; c++) qf[c] = *(const short8*)(qp + 16 * c);
    }

    f32x16 O0 = {}, O1 = {};    // O^T tiles: d in [0,32) / [32,64)
    float mrun = -1e30f, lrun = 0.f;

    int jmax = (qrow0 >> 6) + 1;          // KV tiles of 64
    for (int j = 0; j < jmax; ++j) {
        int k0 = j << 6;
        // K as A-operand: kf{t}[c] = K[k0+32t+lq][16c+8hi..+7]
        short8 kf0[4], kf1[4];
        {
            const ushort_t* kp0 = Kp + base + (size_t)(k0 + lq) * DMODEL + 8 * hi;
            const ushort_t* kp1 = kp0 + (size_t)32 * DMODEL;
#pragma unroll
            for (int c = 0; c < 4; c++) { kf0[c] = *(const short8*)(kp0 + 16 * c);
                                          kf1[c] = *(const short8*)(kp1 + 16 * c); }
        }
        // V^T as A-operand: vf{dt}[c] = VT[32dt+lq][k0+16c+8hi..+7]
        short8 vf0[4], vf1[4];
        {
            const ushort_t* vp0 = VT + baseT + (size_t)lq * NSEQ + k0 + 8 * hi;
            const ushort_t* vp1 = vp0 + (size_t)32 * NSEQ;
#pragma unroll
            for (int c = 0; c < 4; c++) { vf0[c] = *(const short8*)(vp0 + 16 * c);
                                          vf1[c] = *(const short8*)(vp1 + 16 * c); }
        }
        // ---- QK^T (swapped): two 32k x 32q tiles ----
        f32x16 S0 = {}, S1 = {};
#pragma unroll
        for (int c = 0; c < 4; c++) S0 = __builtin_amdgcn_mfma_f32_32x32x16_bf16(kf0[c], qf[c], S0, 0, 0, 0);
#pragma unroll
        for (int c = 0; c < 4; c++) S1 = __builtin_amdgcn_mfma_f32_32x32x16_bf16(kf1[c], qf[c], S1, 0, 0, 0);

        if (j == jmax - 1) {    // causal mask (diagonal tiles only)
#pragma unroll
            for (int r = 0; r < 16; r++) {
                int kk = k0 + (r & 3) + 8 * (r >> 2) + 4 * hi;
                if (kk > qg)      S0[r] = -1e30f;
                if (kk + 32 > qg) S1[r] = -1e30f;
            }
        }
        // ---- online softmax (exp2 domain), row = q fully lane-local + 1 swap ----
        float mx = -1e30f;
#pragma unroll
        for (int r = 0; r < 16; r++) mx = fmaxf(mx, fmaxf(S0[r], S1[r]));
        mx = fmaxf(mx, __shfl_xor(mx, 32));
        float mn = fmaxf(mrun, mx);
        float sc = __builtin_amdgcn_exp2f(mrun - mn);
        mrun = mn;
        float rs0 = 0.f, rs1 = 0.f;
#pragma unroll
        for (int r = 0; r < 16; r++) {
            S0[r] = __builtin_amdgcn_exp2f(S0[r] - mn);
            S1[r] = __builtin_amdgcn_exp2f(S1[r] - mn);
            rs0 += S0[r]; rs1 += S1[r];
        }
        float rs = rs0 + rs1;
        rs += __shfl_xor(rs, 32);
        lrun = lrun * sc + rs;
        O0 *= sc; O1 *= sc;
        // ---- P^T -> B-operand frags: cvt_pk + permlane32_swap (T12) ----
        unsigned pw0[8], pw1[8];
#pragma unroll
        for (int jj = 0; jj < 8; jj++) {
            pw0[jj] = cvt_pk_bf16(S0[2 * jj], S0[2 * jj + 1]);
            pw1[jj] = cvt_pk_bf16(S1[2 * jj], S1[2 * jj + 1]);
        }
        short8 pfr[4];
        {
            union U { unsigned u[4]; short8 s; };
            int2v a, bb;
            a  = __builtin_amdgcn_permlane32_swap((int)pw0[0], (int)pw0[2], false, false);
            bb = __builtin_amdgcn_permlane32_swap((int)pw0[1], (int)pw0[3], false, false);
            U u0; u0.u[0] = (unsigned)a[0]; u0.u[1] = (unsigned)bb[0];
                  u0.u[2] = (unsigned)a[1]; u0.u[3] = (unsigned)bb[1];
            pfr[0] = u0.s;
            a  = __builtin_amdgcn_permlane32_swap((int)pw0[4], (int)pw0[6], false, false);
            bb = __builtin_amdgcn_permlane32_swap((int)pw0[5], (int)pw0[7], false, false);
            U u1; u1.u[0] = (unsigned)a[0]; u1.u[1] = (unsigned)bb[0];
                  u1.u[2] = (unsigned)a[1]; u1.u[3] = (unsigned)bb[1];
            pfr[1] = u1.s;
            a  = __builtin_amdgcn_permlane32_swap((int)pw1[0], (int)pw1[2], false, false);
            bb = __builtin_amdgcn_permlane32_swap((int)pw1[1], (int)pw1[3], false, false);
            U u2; u2.u[0] = (unsigned)a[0]; u2.u[1] = (unsigned)bb[0];
                  u2.u[2] = (unsigned)a[1]; u2.u[3] = (unsigned)bb[1];
            pfr[2] = u2.s;
            a  = __builtin_amdgcn_permlane32_swap((int)pw1[4], (int)pw1[6], false, false);
            bb = __builtin_amdgcn_permlane32_swap((int)pw1[5], (int)pw1[7], false, false);
            U u3; u3.u[0] = (unsigned)a[0]; u3.u[1] = (unsigned)bb[0];
                  u3.u[2] = (unsigned)a[1]; u3.u[3] = (unsigned)bb[1];
            pfr[3] = u3.s;
        }
        // ---- PV: O^T += V^T P^T ----
#pragma unroll
        for (int c = 0; c < 4; c++) O0 = __builtin_amdgcn_mfma_f32_32x32x16_bf16(vf0[c], pfr[c], O0, 0, 0, 0);
#pragma unroll
        for (int c = 0; c < 4; c++) O1 = __builtin_amdgcn_mfma_f32_32x32x16_bf16(vf1[c], pfr[c], O1, 0, 0, 0);
    }
    // ---- epilogue: lane holds O^T[d][q=lq]; d = (r&3)+8*(r>>2)+4hi+32dt ----
    float inv = 1.f / lrun;
    size_t rowoff = base + (size_t)qg * DMODEL;
#pragma unroll
    for (int q4 = 0; q4 < 4; q4++) {
        unsigned a0 = (unsigned)f2bf(O0[4 * q4] * inv)     | ((unsigned)f2bf(O0[4 * q4 + 1] * inv) << 16);
        unsigned a1 = (unsigned)f2bf(O0[4 * q4 + 2] * inv) | ((unsigned)f2bf(O0[4 * q4 + 3] * inv) << 16);
        uint2 ua = {a0, a1};
        *(uint2*)(AO + rowoff + 8 * q4 + 4 * hi) = ua;
        unsigned b0 = (unsigned)f2bf(O1[4 * q4] * inv)     | ((unsigned)f2bf(O1[4 * q4 + 1] * inv) << 16);
        unsigned b1 = (unsigned)f2bf(O1[4 * q4 + 2] * inv) | ((unsigned)f2bf(O1[4 * q4 + 3] * inv) << 16);
        uint2 ub = {b0, b1};
        *(uint2*)(AO + rowoff + 32 + 8 * q4 + 4 * hi) = ub;
    }
}

// ---------------- launch ----------------
extern "C" void kernel_launch(void* const* d_in, const int* in_sizes, int n_in,
                              void* d_out, int out_size, void* d_ws, size_t ws_size,
                              hipStream_t stream) {
    const float* q  = (const float*)d_in[0];
    const float* k  = (const float*)d_in[1];
    const float* v  = (const float*)d_in[2];
    const float* Wq = (const float*)d_in[3];
    const float* Wk = (const float*)d_in[4];
    const float* Wv = (const float*)d_in[5];
    const float* Wo = (const float*)d_in[6];
    float* out = (float*)d_out;

    const size_t BND = (size_t)BATCH * NSEQ * DMODEL;   // 8388608
    const size_t WSZ = (size_t)DMODEL * DMODEL;         // 1048576
    const size_t need = (7 * BND + 4 * WSZ) * sizeof(ushort_t);  // ~120 MB
    if (ws_size < need) return;

    ushort_t* ws  = (ushort_t*)d_ws;
    ushort_t* qb  = ws;
    ushort_t* kb  = qb + BND;
    ushort_t* vb  = kb + BND;
    ushort_t* Qp  = vb + BND;
    ushort_t* Kp  = Qp + BND;
    ushort_t* VT  = Kp + BND;   // V projection, transposed layout [B*D][NSEQ]
    ushort_t* AO  = VT + BND;
    ushort_t* Wqb = AO + BND;
    ushort_t* Wkb = Wqb + WSZ;
    ushort_t* Wvb = Wkb + WSZ;
    ushort_t* Wob = Wvb + WSZ;

    const int M = BATCH * NSEQ;  // 8192

    cvt_f32_bf16<<<(int)(BND / 8 / 256), 256, 0, stream>>>(q, qb, (int)BND);
    cvt_f32_bf16<<<(int)(BND / 8 / 256), 256, 0, stream>>>(k, kb, (int)BND);
    cvt_f32_bf16<<<(int)(BND / 8 / 256), 256, 0, stream>>>(v, vb, (int)BND);
    cvt_f32_bf16<<<(int)(WSZ / 8 / 256), 256, 0, stream>>>(Wq, Wqb, (int)WSZ);
    cvt_f32_bf16<<<(int)(WSZ / 8 / 256), 256, 0, stream>>>(Wk, Wkb, (int)WSZ);
    cvt_f32_bf16<<<(int)(WSZ / 8 / 256), 256, 0, stream>>>(Wv, Wvb, (int)WSZ);
    cvt_f32_bf16<<<(int)(WSZ / 8 / 256), 256, 0, stream>>>(Wo, Wob, (int)WSZ);

    int gblocks = (M / 128) * (DMODEL / 128);  // 512
    // scores scale 1/sqrt(64) * log2(e) folded into Q projection (exp2-domain softmax)
    gemm_bt<ushort_t, false><<<gblocks, 256, 0, stream>>>(qb, Wqb, Qp, M, DMODEL, DMODEL, 0.18033688011112043f);
    gemm_bt<ushort_t, false><<<gblocks, 256, 0, stream>>>(kb, Wkb, Kp, M, DMODEL, DMODEL, 1.0f);
    gemm_bt<ushort_t, true ><<<gblocks, 256, 0, stream>>>(vb, Wvb, VT, M, DMODEL, DMODEL, 1.0f);

    attn_kernel<<<BATCH * NHEAD * (NSEQ / 128), 256, 0, stream>>>(Qp, Kp, VT, AO);

    gemm_bt<float, false><<<gblocks, 256, 0, stream>>>(AO, Wob, out, M, DMODEL, DMODEL, 1.0f);
}